// Round 1
// baseline (1250.449 us; speedup 1.0000x reference)
//
#include <hip/hip_runtime.h>

#define CLAMP_MIN_F (-10.0f)
#define CLAMP_MAX_F (10.0f)
#define BATCH 8

// Kernel 1: initialize chem accumulator in workspace with chem_influence.
__global__ void init_chem_kernel(const float* __restrict__ chem_in,
                                 float* __restrict__ chem,
                                 int total) {
    int i = blockIdx.x * blockDim.x + threadIdx.x;
    if (i < total) chem[i] = chem_in[i];
}

// Kernel 2: edge scatter-add. One thread per edge, inner loop over batches.
__global__ void edge_scatter_kernel(const int* __restrict__ src,
                                    const int* __restrict__ dst,
                                    const float* __restrict__ w,
                                    const float* __restrict__ o_pre,
                                    const float* __restrict__ E,
                                    float* __restrict__ chem,
                                    int edges, int N) {
    int e = blockIdx.x * blockDim.x + threadIdx.x;
    if (e >= edges) return;
    int s = src[e];
    int d = dst[e];
    float we = w[e];
    #pragma unroll
    for (int b = 0; b < BATCH; ++b) {
        int base = b * N;
        float Oj = o_pre[base + s];
        float En = E[base + d];
        float diff = Oj - En;
        float sg = (diff > 0.0f) ? 1.0f : ((diff < 0.0f) ? -1.0f : 0.0f);
        float contrib = Oj * we * sg;
        atomicAdd(&chem[base + d], contrib);
    }
}

// Kernel 3: elementwise finalize producing new_o and new_e.
__global__ void finalize_kernel(const float* __restrict__ E,
                                const float* __restrict__ chem,
                                const float* __restrict__ thr,
                                const float* __restrict__ decay,
                                float* __restrict__ new_o,
                                float* __restrict__ new_e,
                                int N, int total) {
    int i = blockIdx.x * blockDim.x + threadIdx.x;
    if (i >= total) return;
    int n = i % N;  // column index for threshold/decay
    float e  = E[i];
    float S  = e + chem[i];
    S = fminf(fmaxf(S, CLAMP_MIN_F), CLAMP_MAX_F);
    float t  = thr[n];
    bool  gt = S > t;
    float no = fmaxf(S - t, 0.0f);
    float ne;
    if (gt) {
        ne = no;
    } else if (S == e) {
        ne = e - decay[n];
    } else {
        ne = S;
    }
    new_o[i] = no;
    new_e[i] = ne;
}

extern "C" void kernel_launch(void* const* d_in, const int* in_sizes, int n_in,
                              void* d_out, int out_size, void* d_ws, size_t ws_size,
                              hipStream_t stream) {
    // Input order (setup_inputs): chem_influence, E, O, src, dst, w, o_pre, threshold, decay
    const float* chem_influence = (const float*)d_in[0];
    const float* E              = (const float*)d_in[1];
    // d_in[2] = O, unused by the reference computation
    const int*   src            = (const int*)d_in[3];
    const int*   dst            = (const int*)d_in[4];
    const float* w              = (const float*)d_in[5];
    const float* o_pre          = (const float*)d_in[6];
    const float* threshold      = (const float*)d_in[7];
    const float* decay          = (const float*)d_in[8];

    const int edges = in_sizes[3];
    const int BN    = in_sizes[0];        // B * N
    const int N     = in_sizes[7];        // threshold is (N,)

    float* chem  = (float*)d_ws;          // B*N floats of scratch
    float* new_o = (float*)d_out;         // first output
    float* new_e = (float*)d_out + BN;    // second output

    const int TB = 256;

    // 1) chem = chem_influence
    init_chem_kernel<<<(BN + TB - 1) / TB, TB, 0, stream>>>(chem_influence, chem, BN);

    // 2) scatter-add contributions over edges
    edge_scatter_kernel<<<(edges + TB - 1) / TB, TB, 0, stream>>>(
        src, dst, w, o_pre, E, chem, edges, N);

    // 3) finalize elementwise
    finalize_kernel<<<(BN + TB - 1) / TB, TB, 0, stream>>>(
        E, chem, threshold, decay, new_o, new_e, N, BN);
}